// Round 5
// baseline (314.176 us; speedup 1.0000x reference)
//
#include <hip/hip_runtime.h>
#include <float.h>
#include <math.h>

// VQ nearest-codebook: z_e (64,256,32,32) fp32 NCHW, codebook (512,256) fp32.
// token t = n*1024 + hw; feature d at z_e[n*262144 + d*1024 + hw].
// d_out: [0,65536) = q as float; [65536,...) = z_q fp32 NCHW.
//
// Ref model (proven R3/R4): ref dists quantized by fp32 expansion (xsq~256);
// scan approximates m = x.w - 0.5|w|^2 via bf16-split 3-pass MFMA (err ~1e-7),
// top-4 per token; if m-gap > MARGIN the argmax is final; else replicate the
// np fp32 quantized distance (xsq/wsq np-pairwise, fp64 dot -> fp32), tie->low k.

#define KCODES 512
#define DDIM   256
#define HWSZ   1024
#define TTOK   65536
#define TPB    64             // tokens per block
#define NBLK   (TTOK / TPB)   // 1024
#define NCHUNK 16             // k-chunks of 16 dims
#define MARGIN 2.5e-4f
#define SCW    264            // padded score row stride (words)

typedef short bf16x8 __attribute__((ext_vector_type(8)));   // 8 bf16 (4 VGPRs)
typedef float f32x16 __attribute__((ext_vector_type(16)));

__device__ inline unsigned short bf16rne(float x) {
    union { float f; unsigned u; } a; a.f = x;
    unsigned r = a.u + (0x7fffu + ((a.u >> 16) & 1u));
    return (unsigned short)(r >> 16);
}
__device__ inline float bf16tof(unsigned short h) {
    union { unsigned u; float f; } b; b.u = ((unsigned)h) << 16; return b.f;
}

// ---------------------------------------------------------------- prep -----
// One block per code row: pack B bf16 hi/lo fragments + hv[k] = 0.5*||w||^2.
// wsw layout: [chunk c:16][part p:2][tile:16][lane:64][16B]  (512 KiB)
// element: code = tile*32 + (lane&31), d = c*16 + (lane>>5)*8 + j
__global__ __launch_bounds__(64) void vq_prep(const float* __restrict__ cb,
                                              float* __restrict__ hv,
                                              unsigned char* __restrict__ wsw) {
    const int k = blockIdx.x;
    const int lane = threadIdx.x;
    const int o = lane & 31, p = lane >> 5;
    const float4* row4 = (const float4*)(cb + (size_t)k * DDIM);
    float4 a = row4[o * 2], b = row4[o * 2 + 1];
    float v[8] = {a.x, a.y, a.z, a.w, b.x, b.y, b.z, b.w};

    unsigned hi[4], lo[4];
    #pragma unroll
    for (int jj = 0; jj < 4; ++jj) {
        unsigned short h0 = bf16rne(v[2 * jj]), h1 = bf16rne(v[2 * jj + 1]);
        unsigned short l0 = bf16rne(v[2 * jj] - bf16tof(h0));
        unsigned short l1 = bf16rne(v[2 * jj + 1] - bf16tof(h1));
        hi[jj] = (unsigned)h0 | ((unsigned)h1 << 16);
        lo[jj] = (unsigned)l0 | ((unsigned)l1 << 16);
    }
    const int c = o >> 1, half = o & 1;
    const int tile = k >> 5, lane2 = (k & 31) + 32 * half;
    uint4 val = p ? make_uint4(lo[0], lo[1], lo[2], lo[3])
                  : make_uint4(hi[0], hi[1], hi[2], hi[3]);
    *(uint4*)(wsw + ((size_t)((c * 2 + p) * 16 + tile) * 1024) + lane2 * 16) = val;

    // hv: lanes 0..31 cover all 256 dims; 32..63 duplicate -> butterfly = 2*||w||^2
    float s = 0.f;
    #pragma unroll
    for (int j = 0; j < 8; ++j) s = fmaf(v[j], v[j], s);
    #pragma unroll
    for (int off = 1; off <= 32; off <<= 1) s += __shfl_xor(s, off);
    if (lane == 0) hv[k] = 0.25f * s;
}

// ---------------------------------------------------------------- main -----
// 1024 blocks x 512 threads (8 waves). Block = 64 tokens x 512 codes.
// Wave wv: codes [wv*64, wv*64+64) = B tiles 2wv, 2wv+1.
// A LDS layout: [p:2][mt:2][c:16][lane:64][16B] = 64 KiB.
__global__ __launch_bounds__(512, 4) void vq_main(const float* __restrict__ z_e,
                                                  const float* __restrict__ cb,
                                                  const float* __restrict__ hv,
                                                  const unsigned char* __restrict__ wsw,
                                                  float* __restrict__ out) {
    __shared__ __align__(16) unsigned char lds[67584];
    float* scf = (float*)lds;

    const int tid = threadIdx.x;
    const int wv = tid >> 6, lane = tid & 63;
    const int tbase = blockIdx.x * TPB;
    const int n = tbase >> 10, hw0 = tbase & (HWSZ - 1);
    const float* zb = z_e + (size_t)n * (DDIM * HWSZ) + hw0;

    // ---- stage x -> LDS: wave wv handles dims [wv*32, wv*32+32), lane = token
    {
        const int tok = lane;
        const int mt = tok >> 5;
        const int off0 = (tok & 31) * 16;
        float v[4][8];
        #pragma unroll
        for (int o = 0; o < 4; ++o)
            #pragma unroll
            for (int j = 0; j < 8; ++j)
                v[o][j] = zb[(size_t)(wv * 32 + o * 8 + j) * HWSZ + tok];
        #pragma unroll
        for (int o = 0; o < 4; ++o) {
            const int d0 = wv * 32 + o * 8;
            unsigned hi[4], lo[4];
            #pragma unroll
            for (int jj = 0; jj < 4; ++jj) {
                unsigned short h0 = bf16rne(v[o][2 * jj]), h1 = bf16rne(v[o][2 * jj + 1]);
                unsigned short l0 = bf16rne(v[o][2 * jj] - bf16tof(h0));
                unsigned short l1 = bf16rne(v[o][2 * jj + 1] - bf16tof(h1));
                hi[jj] = (unsigned)h0 | ((unsigned)h1 << 16);
                lo[jj] = (unsigned)l0 | ((unsigned)l1 << 16);
            }
            const int c = d0 >> 4;
            const int off2 = off0 + 512 * ((d0 >> 3) & 1);
            *(uint4*)(lds + ((0 * 2 + mt) * 16 + c) * 1024 + off2) = make_uint4(hi[0], hi[1], hi[2], hi[3]);
            *(uint4*)(lds + ((1 * 2 + mt) * 16 + c) * 1024 + off2) = make_uint4(lo[0], lo[1], lo[2], lo[3]);
        }
    }

    f32x16 acc[2][2];
    #pragma unroll
    for (int mt = 0; mt < 2; ++mt)
        #pragma unroll
        for (int nt = 0; nt < 2; ++nt)
            #pragma unroll
            for (int r = 0; r < 16; ++r) acc[mt][nt][r] = 0.f;

    __syncthreads();

    // ---- K-loop: 16 chunks of 16 dims, 3 bf16-split passes, B from L2 ----
    #define LDB(c, p, nt) (*(const bf16x8*)(wsw + ((size_t)(((c) * 2 + (p)) * 16 + (wv * 2 + (nt))) * 1024) + lane * 16))
    #define LDA(p, mt, c) (*(const bf16x8*)(lds + (((p) * 2 + (mt)) * 16 + (c)) * 1024 + lane * 16))

    #pragma unroll
    for (int c = 0; c < NCHUNK; ++c) {
        bf16x8 Bh0 = LDB(c, 0, 0), Bh1 = LDB(c, 0, 1);
        bf16x8 Bl0 = LDB(c, 1, 0), Bl1 = LDB(c, 1, 1);
        bf16x8 Ah0 = LDA(0, 0, c), Ah1 = LDA(0, 1, c);
        bf16x8 Al0 = LDA(1, 0, c), Al1 = LDA(1, 1, c);
        acc[0][0] = __builtin_amdgcn_mfma_f32_32x32x16_bf16(Ah0, Bh0, acc[0][0], 0, 0, 0);
        acc[0][1] = __builtin_amdgcn_mfma_f32_32x32x16_bf16(Ah0, Bh1, acc[0][1], 0, 0, 0);
        acc[1][0] = __builtin_amdgcn_mfma_f32_32x32x16_bf16(Ah1, Bh0, acc[1][0], 0, 0, 0);
        acc[1][1] = __builtin_amdgcn_mfma_f32_32x32x16_bf16(Ah1, Bh1, acc[1][1], 0, 0, 0);
        acc[0][0] = __builtin_amdgcn_mfma_f32_32x32x16_bf16(Ah0, Bl0, acc[0][0], 0, 0, 0);
        acc[0][1] = __builtin_amdgcn_mfma_f32_32x32x16_bf16(Ah0, Bl1, acc[0][1], 0, 0, 0);
        acc[1][0] = __builtin_amdgcn_mfma_f32_32x32x16_bf16(Ah1, Bl0, acc[1][0], 0, 0, 0);
        acc[1][1] = __builtin_amdgcn_mfma_f32_32x32x16_bf16(Ah1, Bl1, acc[1][1], 0, 0, 0);
        acc[0][0] = __builtin_amdgcn_mfma_f32_32x32x16_bf16(Al0, Bh0, acc[0][0], 0, 0, 0);
        acc[0][1] = __builtin_amdgcn_mfma_f32_32x32x16_bf16(Al0, Bh1, acc[0][1], 0, 0, 0);
        acc[1][0] = __builtin_amdgcn_mfma_f32_32x32x16_bf16(Al1, Bh0, acc[1][0], 0, 0, 0);
        acc[1][1] = __builtin_amdgcn_mfma_f32_32x32x16_bf16(Al1, Bh1, acc[1][1], 0, 0, 0);
    }

    // ---- epilogue: scores -> padded LDS (2 rounds), conflict-free fold ----
    const float hv0 = hv[wv * 64 + (lane & 31)];
    const float hv1 = hv[wv * 64 + 32 + (lane & 31)];

    float fb[4] = {-FLT_MAX, -FLT_MAX, -FLT_MAX, -FLT_MAX};
    int   fi[4] = {KCODES, KCODES, KCODES, KCODES};
    const int tk = tid >> 3, q = tid & 7;

    #pragma unroll
    for (int r = 0; r < 2; ++r) {
        __syncthreads();
        if ((wv >> 2) == r) {
            const int clA = (wv & 3) * 64 + (lane & 31);
            const int rowb = 4 * (lane >> 5);
            #pragma unroll
            for (int mt = 0; mt < 2; ++mt)
                #pragma unroll
                for (int nt = 0; nt < 2; ++nt) {
                    const float h2 = nt ? hv1 : hv0;
                    #pragma unroll
                    for (int reg = 0; reg < 16; ++reg) {
                        const int tok = mt * 32 + (reg & 3) + 8 * (reg >> 2) + rowb;
                        scf[tok * SCW + clA + nt * 32] = acc[mt][nt][reg] - h2;
                    }
                }
        }
        __syncthreads();
        #pragma unroll 8
        for (int i = 0; i < 32; ++i) {
            const int col = q + 8 * i;                 // bank = (8*tk + q) -> 2-way max
            const float m = scf[tk * SCW + col];
            const int code = r * 256 + col;
            if (m > fb[3]) {
                if (m > fb[1]) {
                    if (m > fb[0]) {
                        fb[3]=fb[2]; fi[3]=fi[2]; fb[2]=fb[1]; fi[2]=fi[1];
                        fb[1]=fb[0]; fi[1]=fi[0]; fb[0]=m; fi[0]=code;
                    } else {
                        fb[3]=fb[2]; fi[3]=fi[2]; fb[2]=fb[1]; fi[2]=fi[1];
                        fb[1]=m; fi[1]=code;
                    }
                } else {
                    if (m > fb[2]) { fb[3]=fb[2]; fi[3]=fi[2]; fb[2]=m; fi[2]=code; }
                    else           { fb[3]=m; fi[3]=code; }
                }
            }
        }
    }

    // ---- publish per-thread top-4, merge per token, adjudicate ----
    __syncthreads();
    float* candm = scf;                    // 2048 floats
    int*   candi = (int*)(scf + 2048);     // 2048 ints
    int*   bkArr = (int*)(scf + 4096);     // 64 ints
    #pragma unroll
    for (int c = 0; c < 4; ++c) { candm[tid * 4 + c] = fb[c]; candi[tid * 4 + c] = fi[c]; }
    __syncthreads();

    if (tid < TPB) {
        float g[4] = {-FLT_MAX, -FLT_MAX, -FLT_MAX, -FLT_MAX};
        int  gi[4] = {KCODES, KCODES, KCODES, KCODES};
        #pragma unroll
        for (int e = 0; e < 32; ++e) {
            const float m = candm[(tid * 8 + (e >> 2)) * 4 + (e & 3)];
            const int idx = candi[(tid * 8 + (e >> 2)) * 4 + (e & 3)];
            if (m > g[3]) {
                if (m > g[1]) {
                    if (m > g[0]) { g[3]=g[2]; gi[3]=gi[2]; g[2]=g[1]; gi[2]=gi[1];
                                    g[1]=g[0]; gi[1]=gi[0]; g[0]=m; gi[0]=idx; }
                    else          { g[3]=g[2]; gi[3]=gi[2]; g[2]=g[1]; gi[2]=gi[1];
                                    g[1]=m; gi[1]=idx; }
                } else {
                    if (m > g[2]) { g[3]=g[2]; gi[3]=gi[2]; g[2]=m; gi[2]=idx; }
                    else          { g[3]=m; gi[3]=idx; }
                }
            }
        }

        int bestk;
        if (g[0] - g[1] > MARGIN) {
            bestk = gi[0];     // gap >> quantization window: no tie possible
        } else {
            const float* xa = zb + tid;
            // xsq: bitwise np pairwise fp32
            float xsq;
            {
#pragma clang fp contract(off)
                float sh[2];
                #pragma unroll
                for (int h = 0; h < 2; ++h) {
                    float rr[8];
                    #pragma unroll
                    for (int j = 0; j < 8; ++j) { float v = xa[(size_t)(h * 128 + j) * HWSZ]; rr[j] = v * v; }
                    #pragma unroll 2
                    for (int i = 8; i < 128; i += 8) {
                        #pragma unroll
                        for (int j = 0; j < 8; ++j) {
                            float v = xa[(size_t)(h * 128 + i + j) * HWSZ];
                            float sq = v * v;
                            rr[j] = rr[j] + sq;
                        }
                    }
                    sh[h] = ((rr[0] + rr[1]) + (rr[2] + rr[3])) + ((rr[4] + rr[5]) + (rr[6] + rr[7]));
                }
                xsq = sh[0] + sh[1];
            }
            float bestd = FLT_MAX; bestk = KCODES;
            for (int c = 0; c < 4; ++c) {
                if (c > 0 && g[0] - g[c] > MARGIN) break;
                const int idx = gi[c];
                const float* wr = cb + (size_t)idx * DDIM;
                // fp64 near-exact dot
                double A = 0.0;
                #pragma unroll 4
                for (int d = 0; d < DDIM; ++d)
                    A = fma((double)xa[(size_t)d * HWSZ], (double)wr[d], A);
                // wsq: bitwise np pairwise fp32 (inline, row contiguous)
                float wsqv;
                {
#pragma clang fp contract(off)
                    float sh[2];
                    #pragma unroll
                    for (int h = 0; h < 2; ++h) {
                        float rr[8];
                        #pragma unroll
                        for (int j = 0; j < 8; ++j) { float v = wr[h * 128 + j]; rr[j] = v * v; }
                        #pragma unroll 2
                        for (int i = 8; i < 128; i += 8) {
                            #pragma unroll
                            for (int j = 0; j < 8; ++j) {
                                float v = wr[h * 128 + i + j];
                                float sq = v * v;
                                rr[j] = rr[j] + sq;
                            }
                        }
                        sh[h] = ((rr[0] + rr[1]) + (rr[2] + rr[3])) + ((rr[4] + rr[5]) + (rr[6] + rr[7]));
                    }
                    wsqv = sh[0] + sh[1];
                }
                {
#pragma clang fp contract(off)
                    const float xw = (float)A;
                    const float t1 = xsq - 2.0f * xw;
                    const float dist = t1 + wsqv;
                    if (dist < bestd || (dist == bestd && idx < bestk)) { bestd = dist; bestk = idx; }
                }
            }
        }
        out[tbase + tid] = (float)bestk;
        bkArr[tid] = bestk;
    }
    __syncthreads();

    // ---- z_q write (coalesced over tokens) ----
    {
        const int tok = tid & 63, s = tid >> 6;
        const int bk = bkArr[tok];
        const float* wr = cb + (size_t)bk * DDIM;
        float* zq = out + TTOK + (size_t)n * (DDIM * HWSZ) + hw0 + tok;
        #pragma unroll 8
        for (int i = 0; i < 32; ++i) {
            const int d = s * 32 + i;
            zq[(size_t)d * HWSZ] = wr[d];
        }
    }
}

// --------------------------------------------------------------- launch ----
extern "C" void kernel_launch(void* const* d_in, const int* in_sizes, int n_in,
                              void* d_out, int out_size, void* d_ws, size_t ws_size,
                              hipStream_t stream) {
    const float* z_e = (const float*)d_in[0];
    const float* cb  = (const float*)d_in[1];
    float* out = (float*)d_out;
    float* hv = (float*)d_ws;                               // 2 KiB (0.5*||w||^2)
    unsigned char* wsw = (unsigned char*)d_ws + 2048;       // 512 KiB fragment-packed w

    vq_prep<<<KCODES, 64, 0, stream>>>(cb, hv, wsw);
    vq_main<<<NBLK, 512, 0, stream>>>(z_e, cb, hv, wsw, out);
}